// Round 1
// baseline (1875.760 us; speedup 1.0000x reference)
//
#include <hip/hip_runtime.h>
#include <math.h>

#define N_NODES_C 50000
#define N_EDGES_C 150000
#define N_GRAPHS_C 64
#define HDIM 128

// ---------------- Tiled f32 GEMM: C = A[M,K] @ B[K,N] + bias, batched over z ----------------
#define BM 64
#define BN 64
#define BK 16

__global__ __launch_bounds__(256) void gemm_bias_kernel(
    const float* __restrict__ A, int lda, long sA,
    const float* __restrict__ B, int ldb, long sB,
    const float* __restrict__ bias,
    float* __restrict__ C, int ldc, long sC,
    int M, int K,
    int epilogue,                       // 0 none, 1 relu, 2 gated-skip + relu
    const float* __restrict__ skipGate, // scalar (pre-sigmoid)
    const float* __restrict__ Xprev)    // skip source, ld == ldc
{
    int bz = blockIdx.z;
    A += (long)bz * sA;
    B += (long)bz * sB;
    C += (long)bz * sC;

    __shared__ float As[BK][BM + 4];
    __shared__ float Bs[BK][BN + 4];

    const int t = threadIdx.x;
    const int row0 = blockIdx.y * BM;
    const int col0 = blockIdx.x * BN;
    const int tm = (t >> 4) << 2;
    const int tn = (t & 15) << 2;

    float acc[4][4] = {};

    for (int k0 = 0; k0 < K; k0 += BK) {
        #pragma unroll
        for (int i = 0; i < 4; ++i) {
            int idx = t + i * 256;
            int m = idx >> 4;
            int kk = idx & 15;
            int gm = row0 + m;
            float v = 0.f;
            if (gm < M) v = A[(long)gm * lda + (k0 + kk)];
            As[kk][m] = v;
        }
        #pragma unroll
        for (int i = 0; i < 4; ++i) {
            int idx = t + i * 256;
            int kk = idx >> 6;
            int n = idx & 63;
            Bs[kk][n] = B[(long)(k0 + kk) * ldb + (col0 + n)];
        }
        __syncthreads();
        #pragma unroll
        for (int kk = 0; kk < BK; ++kk) {
            float a[4], b[4];
            #pragma unroll
            for (int i = 0; i < 4; ++i) a[i] = As[kk][tm + i];
            #pragma unroll
            for (int j = 0; j < 4; ++j) b[j] = Bs[kk][tn + j];
            #pragma unroll
            for (int i = 0; i < 4; ++i)
                #pragma unroll
                for (int j = 0; j < 4; ++j)
                    acc[i][j] = fmaf(a[i], b[j], acc[i][j]);
        }
        __syncthreads();
    }

    float gate = 0.f;
    if (epilogue == 2) gate = 1.f / (1.f + expf(-skipGate[0]));

    #pragma unroll
    for (int i = 0; i < 4; ++i) {
        int gm = row0 + tm + i;
        if (gm >= M) continue;
        #pragma unroll
        for (int j = 0; j < 4; ++j) {
            int gn = col0 + tn + j;
            float v = acc[i][j];
            if (bias) v += bias[gn];
            if (epilogue == 2) v = gate * v + (1.f - gate) * Xprev[(long)gm * ldc + gn];
            if (epilogue >= 1) v = fmaxf(v, 0.f);
            C[(long)gm * ldc + gn] = v;
        }
    }
}

// ---------------- Edge attention pass: one wave per (edge, head) ----------------
__global__ __launch_bounds__(256) void edge_attn_kernel(
    const int* __restrict__ src, const int* __restrict__ dst,
    const float* __restrict__ q, const float* __restrict__ kr,
    const float* __restrict__ vr,
    const float* __restrict__ p_rel,   // [2] for this relation
    float* __restrict__ num, float* __restrict__ den,
    int E)
{
    int wid = (int)((blockIdx.x * 256 + threadIdx.x) >> 6);
    int lane = threadIdx.x & 63;
    int e = wid >> 1;
    int h = wid & 1;
    if (e >= E) return;

    int s = src[e];
    int d = dst[e];
    int bs = s * HDIM + h * 64;
    int bd = d * HDIM + h * 64;

    float p = q[bd + lane] * kr[bs + lane];
    #pragma unroll
    for (int off = 32; off; off >>= 1) p += __shfl_xor(p, off, 64);

    float w = expf(p * p_rel[h] * 0.125f);   // 1/sqrt(64) = 0.125

    atomicAdd(&num[bd + lane], w * vr[bs + lane]);
    if (lane == 0) atomicAdd(&den[d * 2 + h], w);
}

// ---------------- out += num / (den + 1e-16) ----------------
__global__ __launch_bounds__(256) void scale_acc_kernel(
    const float* __restrict__ num, const float* __restrict__ den,
    float* __restrict__ out, int total)
{
    int i = blockIdx.x * 256 + threadIdx.x;
    if (i >= total) return;
    out[i] += num[i] / (den[i >> 6] + 1e-16f);
}

// ---------------- exact GELU in place ----------------
__global__ __launch_bounds__(256) void gelu_kernel(float* __restrict__ x, int total)
{
    int i = blockIdx.x * 256 + threadIdx.x;
    if (i >= total) return;
    float v = x[i];
    x[i] = 0.5f * v * (1.f + erff(v * 0.70710678118654752f));
}

// ---------------- pooling ----------------
__device__ inline int lower_bound_i(const int* __restrict__ a, int n, int v)
{
    int lo = 0, hi = n;
    while (lo < hi) {
        int mid = (lo + hi) >> 1;
        if (a[mid] < v) lo = mid + 1; else hi = mid;
    }
    return lo;
}

__global__ void pool_kernel(const float* __restrict__ h, const int* __restrict__ batch,
                            float* __restrict__ s, int N)
{
    int g = blockIdx.x;
    int part = blockIdx.y;
    int c = threadIdx.x;
    int start = lower_bound_i(batch, N, g);
    int end = lower_bound_i(batch, N, g + 1);
    int cnt = end - start;
    int parts = gridDim.y;
    int chunk = (cnt + parts - 1) / parts;
    int a = start + part * chunk;
    int b = a + chunk; if (b > end) b = end;
    if (a >= b) return;
    float sum = 0.f;
    for (int n = a; n < b; ++n) sum += h[(long)n * HDIM + c];
    atomicAdd(&s[g * HDIM + c], sum);
}

__global__ void pool_finalize(const float* __restrict__ s, const int* __restrict__ batch,
                              float* __restrict__ g_out, int N)
{
    int g = blockIdx.x;
    int c = threadIdx.x;
    int start = lower_bound_i(batch, N, g);
    int end = lower_bound_i(batch, N, g + 1);
    float cnt = (float)((end - start) > 1 ? (end - start) : 1);
    g_out[g * HDIM + c] = s[g * HDIM + c] / cnt;
}

// ---------------- host ----------------
extern "C" void kernel_launch(void* const* d_in, const int* in_sizes, int n_in,
                              void* d_out, int out_size, void* d_ws, size_t ws_size,
                              hipStream_t stream)
{
    const float* x      = (const float*)d_in[0];
    const int*   e0     = (const int*)d_in[1];
    const int*   e1     = (const int*)d_in[2];
    const int*   batch  = (const int*)d_in[3];
    const float* W_k1   = (const float*)d_in[4];
    const float* W_q1   = (const float*)d_in[5];
    const float* W_v1   = (const float*)d_in[6];
    const float* a_rel1 = (const float*)d_in[7];
    const float* m_rel1 = (const float*)d_in[8];
    const float* W_a1   = (const float*)d_in[9];
    const float* W_k23  = (const float*)d_in[10];
    const float* W_q23  = (const float*)d_in[11];
    const float* W_v23  = (const float*)d_in[12];
    const float* a_rel23= (const float*)d_in[13];
    const float* m_rel23= (const float*)d_in[14];
    const float* W_a23  = (const float*)d_in[15];
    const float* W_m1   = (const float*)d_in[16];
    const float* W_m2   = (const float*)d_in[17];
    const float* b_k1   = (const float*)d_in[18];
    const float* b_q1   = (const float*)d_in[19];
    const float* b_v1   = (const float*)d_in[20];
    const float* b_a1   = (const float*)d_in[21];
    const float* b_k23  = (const float*)d_in[22];
    const float* b_q23  = (const float*)d_in[23];
    const float* b_v23  = (const float*)d_in[24];
    const float* b_a23  = (const float*)d_in[25];
    const float* skip23 = (const float*)d_in[26];
    const float* b_m1   = (const float*)d_in[27];
    const float* b_m2   = (const float*)d_in[28];
    const float* p_rel1 = (const float*)d_in[29];
    const float* p_rel23= (const float*)d_in[30];

    const int N = N_NODES_C;
    const int E = in_sizes[1] / 2;
    const int F = in_sizes[0] / N;           // 512
    const long NN = (long)N * HDIM;          // 6.4M floats

    float* ws  = (float*)d_ws;
    float* Kb  = ws;
    float* Qb  = Kb + NN;
    float* Vb  = Qb + NN;
    float* ACC = Vb + NN;
    float* KR  = ACC + NN;
    float* VR  = KR + NN;
    float* NUM = VR + NN;
    float* H1  = NUM + NN;
    float* H2  = H1 + NN;
    float* DEN = H2 + NN;                    // N*2
    float* S   = DEN + (long)N * 2;          // 64*128
    float* GM  = S + N_GRAPHS_C * HDIM;
    float* M1  = GM + N_GRAPHS_C * HDIM;
    size_t needed = (size_t)(9 * NN + (long)N * 2 + 3L * N_GRAPHS_C * HDIM) * sizeof(float);
    if (ws_size < needed) return;            // insufficient scratch — fail loudly

    auto gemm = [&](const float* A, int lda, long sA,
                    const float* B, int ldb, long sB,
                    const float* bias, float* C, int ldc, long sC,
                    int M, int Ncols, int K, int batchCnt,
                    int epi, const float* gate, const float* xprev) {
        dim3 grid(Ncols / BN, (M + BM - 1) / BM, batchCnt);
        gemm_bias_kernel<<<grid, 256, 0, stream>>>(A, lda, sA, B, ldb, sB, bias,
                                                   C, ldc, sC, M, K, epi, gate, xprev);
    };

    auto run_layer = [&](const float* hin, int Fin,
                         const float* Wk, const float* bk,
                         const float* Wq, const float* bq,
                         const float* Wv, const float* bv,
                         const float* arel, const float* mrel, const float* prel,
                         const float* Wa, const float* ba,
                         const float* gate, float* hout) {
        gemm(hin, Fin, 0, Wk, HDIM, 0, bk, Kb, HDIM, 0, N, HDIM, Fin, 1, 0, nullptr, nullptr);
        gemm(hin, Fin, 0, Wq, HDIM, 0, bq, Qb, HDIM, 0, N, HDIM, Fin, 1, 0, nullptr, nullptr);
        gemm(hin, Fin, 0, Wv, HDIM, 0, bv, Vb, HDIM, 0, N, HDIM, Fin, 1, 0, nullptr, nullptr);
        hipMemsetAsync(ACC, 0, NN * sizeof(float), stream);
        for (int r = 0; r < 2; ++r) {
            const int* edg = (r == 0) ? e0 : e1;
            const int* src = edg;
            const int* dst = edg + E;
            // k_r / v_r : per-head 64x64 transforms, head-batched
            gemm(Kb, HDIM, 64, arel + (long)r * 8192, 64, 4096, nullptr,
                 KR, HDIM, 64, N, 64, 64, 2, 0, nullptr, nullptr);
            gemm(Vb, HDIM, 64, mrel + (long)r * 8192, 64, 4096, nullptr,
                 VR, HDIM, 64, N, 64, 64, 2, 0, nullptr, nullptr);
            hipMemsetAsync(NUM, 0, NN * sizeof(float), stream);
            hipMemsetAsync(DEN, 0, (size_t)N * 2 * sizeof(float), stream);
            int waves = E * 2;
            int blocks = (waves + 3) / 4;
            edge_attn_kernel<<<blocks, 256, 0, stream>>>(src, dst, Qb, KR, VR,
                                                         prel + r * 2, NUM, DEN, E);
            scale_acc_kernel<<<(int)((NN + 255) / 256), 256, 0, stream>>>(NUM, DEN, ACC, (int)NN);
        }
        gelu_kernel<<<(int)((NN + 255) / 256), 256, 0, stream>>>(ACC, (int)NN);
        gemm(ACC, HDIM, 0, Wa, HDIM, 0, ba, hout, HDIM, 0, N, HDIM, HDIM, 1,
             gate ? 2 : 1, gate, hin);
    };

    // layer 1 (512 -> 128, no skip), then conv2/conv3 (128 -> 128, gated skip)
    run_layer(x, F, W_k1, b_k1, W_q1, b_q1, W_v1, b_v1,
              a_rel1, m_rel1, p_rel1, W_a1, b_a1, nullptr, H1);
    run_layer(H1, HDIM, W_k23, b_k23, W_q23, b_q23, W_v23, b_v23,
              a_rel23, m_rel23, p_rel23, W_a23, b_a23, skip23, H2);
    run_layer(H2, HDIM, W_k23 + 16384, b_k23 + 128, W_q23 + 16384, b_q23 + 128,
              W_v23 + 16384, b_v23 + 128, a_rel23 + 16384, m_rel23 + 16384,
              p_rel23 + 4, W_a23 + 16384, b_a23 + 128, skip23 + 1, H1);

    // global mean pool (batch is sorted)
    hipMemsetAsync(S, 0, (size_t)N_GRAPHS_C * HDIM * sizeof(float), stream);
    dim3 pg(N_GRAPHS_C, 8);
    pool_kernel<<<pg, HDIM, 0, stream>>>(H1, batch, S, N);
    pool_finalize<<<N_GRAPHS_C, HDIM, 0, stream>>>(S, batch, GM, N);

    // MLP: relu(g @ W_m1 + b_m1) @ W_m2 + b_m2
    gemm(GM, HDIM, 0, W_m1, HDIM, 0, b_m1, M1, HDIM, 0, N_GRAPHS_C, HDIM, HDIM, 1, 1, nullptr, nullptr);
    gemm(M1, HDIM, 0, W_m2, 256, 0, b_m2, (float*)d_out, 256, 0, N_GRAPHS_C, 256, HDIM, 1, 0, nullptr, nullptr);
}

// Round 2
// 1535.851 us; speedup vs baseline: 1.2213x; 1.2213x over previous
//
#include <hip/hip_runtime.h>
#include <math.h>

#define N_NODES_C 50000
#define N_GRAPHS_C 64
#define HDIM 128

typedef short bf16x8 __attribute__((ext_vector_type(8)));
typedef short shortx4 __attribute__((ext_vector_type(4)));
typedef float floatx4 __attribute__((ext_vector_type(4)));

// split f32 -> hi (truncated bf16) + lo (bf16 of exact residual)
__device__ inline void cvt_pair(float x, short& h, short& l) {
    union { float f; unsigned u; } a; a.f = x;
    h = (short)(a.u >> 16);
    union { unsigned u; float f; } b; b.u = a.u & 0xFFFF0000u;
    union { float f; unsigned u; } c; c.f = x - b.f;   // exact residual
    l = (short)(c.u >> 16);
}

// ============ split-bf16 MFMA GEMM: C[M,N] = A[M,K] @ BT[N,K]^T + bias ============
#define GBM 128
#define GBN 128
#define GBK 32
#define BKP 40   // padded LDS k-stride (80 B, keeps 16B alignment, ~2-way banks)

__global__ __launch_bounds__(256, 2) void gemm_mfma_split(
    const float* __restrict__ A, int lda,
    const float* __restrict__ BT, int ldbt,
    const float* __restrict__ bias,
    float* __restrict__ C, int ldc,
    int M, int Ntot, int K,
    int epilogue,                        // 0 none, 1 relu, 2 gated-skip + relu
    const float* __restrict__ skipGate,
    const float* __restrict__ Xprev)
{
    __shared__ __align__(16) short AsH[GBM * BKP];
    __shared__ __align__(16) short AsL[GBM * BKP];
    __shared__ __align__(16) short BsH[GBN * BKP];
    __shared__ __align__(16) short BsL[GBN * BKP];

    const int t = threadIdx.x;
    const int lane = t & 63;
    const int wave = t >> 6;
    const int wm = wave & 1, wn = wave >> 1;
    const int quad = lane >> 4, l15 = lane & 15;
    const long row0 = (long)blockIdx.y * GBM;
    const long col0 = (long)blockIdx.x * GBN;

    const int srow = t >> 3;          // 0..31
    const int sk = (t & 7) << 2;      // 0,4,..,28

    floatx4 acc[4][4];
    #pragma unroll
    for (int i = 0; i < 4; ++i)
        #pragma unroll
        for (int j = 0; j < 4; ++j)
            acc[i][j] = (floatx4){0.f, 0.f, 0.f, 0.f};

    for (int k0 = 0; k0 < K; k0 += GBK) {
        #pragma unroll
        for (int p = 0; p < 4; ++p) {
            int r = p * 32 + srow;
            long gr = row0 + r;
            float4 v = {0.f, 0.f, 0.f, 0.f};
            if (gr < M) v = *(const float4*)(A + gr * lda + k0 + sk);
            short h0, h1, h2, h3, l0, l1, l2, l3;
            cvt_pair(v.x, h0, l0); cvt_pair(v.y, h1, l1);
            cvt_pair(v.z, h2, l2); cvt_pair(v.w, h3, l3);
            int off = r * BKP + sk;
            *(shortx4*)&AsH[off] = (shortx4){h0, h1, h2, h3};
            *(shortx4*)&AsL[off] = (shortx4){l0, l1, l2, l3};
        }
        #pragma unroll
        for (int p = 0; p < 4; ++p) {
            int r = p * 32 + srow;
            long gc = col0 + r;
            float4 v = {0.f, 0.f, 0.f, 0.f};
            if (gc < Ntot) v = *(const float4*)(BT + gc * ldbt + k0 + sk);
            short h0, h1, h2, h3, l0, l1, l2, l3;
            cvt_pair(v.x, h0, l0); cvt_pair(v.y, h1, l1);
            cvt_pair(v.z, h2, l2); cvt_pair(v.w, h3, l3);
            int off = r * BKP + sk;
            *(shortx4*)&BsH[off] = (shortx4){h0, h1, h2, h3};
            *(shortx4*)&BsL[off] = (shortx4){l0, l1, l2, l3};
        }
        __syncthreads();

        bf16x8 aH[4], aL[4], bH[4], bL[4];
        #pragma unroll
        for (int i = 0; i < 4; ++i) {
            int off = (wm * 64 + i * 16 + l15) * BKP + quad * 8;
            aH[i] = *(const bf16x8*)&AsH[off];
            aL[i] = *(const bf16x8*)&AsL[off];
        }
        #pragma unroll
        for (int j = 0; j < 4; ++j) {
            int off = (wn * 64 + j * 16 + l15) * BKP + quad * 8;
            bH[j] = *(const bf16x8*)&BsH[off];
            bL[j] = *(const bf16x8*)&BsL[off];
        }
        #pragma unroll
        for (int i = 0; i < 4; ++i)
            #pragma unroll
            for (int j = 0; j < 4; ++j) {
                acc[i][j] = __builtin_amdgcn_mfma_f32_16x16x32_bf16(aH[i], bH[j], acc[i][j], 0, 0, 0);
                acc[i][j] = __builtin_amdgcn_mfma_f32_16x16x32_bf16(aH[i], bL[j], acc[i][j], 0, 0, 0);
                acc[i][j] = __builtin_amdgcn_mfma_f32_16x16x32_bf16(aL[i], bH[j], acc[i][j], 0, 0, 0);
            }
        __syncthreads();
    }

    float gate = 0.f;
    if (epilogue == 2) gate = 1.f / (1.f + expf(-skipGate[0]));

    #pragma unroll
    for (int i = 0; i < 4; ++i) {
        #pragma unroll
        for (int rr = 0; rr < 4; ++rr) {
            long grow = row0 + wm * 64 + i * 16 + quad * 4 + rr;
            if (grow >= M) continue;
            #pragma unroll
            for (int j = 0; j < 4; ++j) {
                long gcol = col0 + wn * 64 + j * 16 + l15;
                if (gcol >= Ntot) continue;
                float v = acc[i][j][rr];
                if (bias) v += bias[gcol];
                if (epilogue == 2) v = gate * v + (1.f - gate) * Xprev[grow * ldc + gcol];
                if (epilogue >= 1) v = fmaxf(v, 0.f);
                C[grow * ldc + gcol] = v;
            }
        }
    }
}

// ============ build fused transposed weight WbigT[640, F] + bias640 ============
// cols: [0,128) q | [128,384) k_r (r,h,e) | [384,640) v_r
__global__ void build_wbigT(
    const float* __restrict__ Wq, const float* __restrict__ bq,
    const float* __restrict__ Wk, const float* __restrict__ bk,
    const float* __restrict__ Wv, const float* __restrict__ bv,
    const float* __restrict__ arel, const float* __restrict__ mrel,
    float* __restrict__ WT, float* __restrict__ bias, int F)
{
    int idx = blockIdx.x * 256 + threadIdx.x;
    if (idx >= F * 640) return;
    int c = idx / F;
    int f = idx - c * F;
    float w, b = 0.f;
    if (c < 128) {
        w = Wq[(long)f * 128 + c];
        b = bq[c];
    } else {
        int cc = c - 128;
        const float* Wsrc; const float* bsrc; const float* T;
        if (cc < 256) { Wsrc = Wk; bsrc = bk; T = arel; }
        else { cc -= 256; Wsrc = Wv; bsrc = bv; T = mrel; }
        int r = cc >> 7, j = cc & 127, h = j >> 6, e = j & 63;
        const float* Trow = T + ((long)(r * 2 + h) * 4096 + e);   // stride 64 over d
        const float* Wrow = Wsrc + (long)f * 128 + h * 64;
        float s = 0.f;
        for (int d = 0; d < 64; ++d) s += Wrow[d] * Trow[(long)d * 64];
        w = s;
        if (f == 0) {
            float sb = 0.f;
            const float* brow = bsrc + h * 64;
            for (int d = 0; d < 64; ++d) sb += brow[d] * Trow[(long)d * 64];
            b = sb;
        }
    }
    WT[idx] = w;               // idx == c*F + f  -> transposed layout
    if (f == 0) bias[c] = b;
}

__global__ void transpose128(const float* __restrict__ W, float* __restrict__ WT)
{
    int idx = blockIdx.x * 256 + threadIdx.x;   // 16384
    int c = idx >> 7, f = idx & 127;
    WT[idx] = W[f * 128 + c];
}

// ============ edge attention: one wave per (edge, head); q/kr/vr ld = 640 ============
__global__ __launch_bounds__(256) void edge_attn_kernel(
    const int* __restrict__ src, const int* __restrict__ dst,
    const float* __restrict__ q, const float* __restrict__ kr,
    const float* __restrict__ vr,
    const float* __restrict__ p_rel,
    float* __restrict__ num, float* __restrict__ den,
    int E)
{
    int wid = (int)((blockIdx.x * 256 + threadIdx.x) >> 6);
    int lane = threadIdx.x & 63;
    int e = wid >> 1;
    int h = wid & 1;
    if (e >= E) return;

    int s = src[e];
    int d = dst[e];
    long bs = (long)s * 640 + h * 64;
    long bd = (long)d * 640 + h * 64;

    float p = q[bd + lane] * kr[bs + lane];
    #pragma unroll
    for (int off = 32; off; off >>= 1) p += __shfl_xor(p, off, 64);

    float w = expf(p * p_rel[h] * 0.125f);   // 1/sqrt(64)

    atomicAdd(&num[(long)d * 128 + h * 64 + lane], w * vr[bs + lane]);
    if (lane == 0) atomicAdd(&den[d * 2 + h], w);
}

__global__ __launch_bounds__(256) void scale_acc_kernel(
    const float* __restrict__ num, const float* __restrict__ den,
    float* __restrict__ out, int total)
{
    int i = blockIdx.x * 256 + threadIdx.x;
    if (i >= total) return;
    out[i] += num[i] / (den[i >> 6] + 1e-16f);
}

__global__ __launch_bounds__(256) void gelu_kernel(float* __restrict__ x, int total)
{
    int i = blockIdx.x * 256 + threadIdx.x;
    if (i >= total) return;
    float v = x[i];
    x[i] = 0.5f * v * (1.f + erff(v * 0.70710678118654752f));
}

// ============ f32 vector GEMM kept for tiny MLP ============
#define BM 64
#define BN 64
#define BK 16
__global__ __launch_bounds__(256) void gemm_bias_kernel(
    const float* __restrict__ A, int lda,
    const float* __restrict__ B, int ldb,
    const float* __restrict__ bias,
    float* __restrict__ C, int ldc,
    int M, int K, int epilogue)
{
    __shared__ float As[BK][BM + 4];
    __shared__ float Bs[BK][BN + 4];
    const int t = threadIdx.x;
    const int row0 = blockIdx.y * BM;
    const int col0 = blockIdx.x * BN;
    const int tm = (t >> 4) << 2;
    const int tn = (t & 15) << 2;
    float acc[4][4] = {};
    for (int k0 = 0; k0 < K; k0 += BK) {
        #pragma unroll
        for (int i = 0; i < 4; ++i) {
            int idx = t + i * 256;
            int m = idx >> 4, kk = idx & 15;
            int gm = row0 + m;
            As[kk][m] = (gm < M) ? A[(long)gm * lda + (k0 + kk)] : 0.f;
        }
        #pragma unroll
        for (int i = 0; i < 4; ++i) {
            int idx = t + i * 256;
            int kk = idx >> 6, n = idx & 63;
            Bs[kk][n] = B[(long)(k0 + kk) * ldb + (col0 + n)];
        }
        __syncthreads();
        #pragma unroll
        for (int kk = 0; kk < BK; ++kk) {
            float a[4], b[4];
            #pragma unroll
            for (int i = 0; i < 4; ++i) a[i] = As[kk][tm + i];
            #pragma unroll
            for (int j = 0; j < 4; ++j) b[j] = Bs[kk][tn + j];
            #pragma unroll
            for (int i = 0; i < 4; ++i)
                #pragma unroll
                for (int j = 0; j < 4; ++j)
                    acc[i][j] = fmaf(a[i], b[j], acc[i][j]);
        }
        __syncthreads();
    }
    #pragma unroll
    for (int i = 0; i < 4; ++i) {
        int gm = row0 + tm + i;
        if (gm >= M) continue;
        #pragma unroll
        for (int j = 0; j < 4; ++j) {
            int gn = col0 + tn + j;
            float v = acc[i][j];
            if (bias) v += bias[gn];
            if (epilogue >= 1) v = fmaxf(v, 0.f);
            C[(long)gm * ldc + gn] = v;
        }
    }
}

// ============ pooling ============
__device__ inline int lower_bound_i(const int* __restrict__ a, int n, int v)
{
    int lo = 0, hi = n;
    while (lo < hi) { int mid = (lo + hi) >> 1; if (a[mid] < v) lo = mid + 1; else hi = mid; }
    return lo;
}

__global__ void pool_kernel(const float* __restrict__ h, const int* __restrict__ batch,
                            float* __restrict__ s, int N)
{
    int g = blockIdx.x, part = blockIdx.y, c = threadIdx.x;
    int start = lower_bound_i(batch, N, g);
    int end = lower_bound_i(batch, N, g + 1);
    int cnt = end - start, parts = gridDim.y;
    int chunk = (cnt + parts - 1) / parts;
    int a = start + part * chunk;
    int b = a + chunk; if (b > end) b = end;
    if (a >= b) return;
    float sum = 0.f;
    for (int n = a; n < b; ++n) sum += h[(long)n * HDIM + c];
    atomicAdd(&s[g * HDIM + c], sum);
}

__global__ void pool_finalize(const float* __restrict__ s, const int* __restrict__ batch,
                              float* __restrict__ g_out, int N)
{
    int g = blockIdx.x, c = threadIdx.x;
    int start = lower_bound_i(batch, N, g);
    int end = lower_bound_i(batch, N, g + 1);
    float cnt = (float)((end - start) > 1 ? (end - start) : 1);
    g_out[g * HDIM + c] = s[g * HDIM + c] / cnt;
}

// ============ host ============
extern "C" void kernel_launch(void* const* d_in, const int* in_sizes, int n_in,
                              void* d_out, int out_size, void* d_ws, size_t ws_size,
                              hipStream_t stream)
{
    const float* x      = (const float*)d_in[0];
    const int*   e0     = (const int*)d_in[1];
    const int*   e1     = (const int*)d_in[2];
    const int*   batch  = (const int*)d_in[3];
    const float* W_k1   = (const float*)d_in[4];
    const float* W_q1   = (const float*)d_in[5];
    const float* W_v1   = (const float*)d_in[6];
    const float* a_rel1 = (const float*)d_in[7];
    const float* m_rel1 = (const float*)d_in[8];
    const float* W_a1   = (const float*)d_in[9];
    const float* W_k23  = (const float*)d_in[10];
    const float* W_q23  = (const float*)d_in[11];
    const float* W_v23  = (const float*)d_in[12];
    const float* a_rel23= (const float*)d_in[13];
    const float* m_rel23= (const float*)d_in[14];
    const float* W_a23  = (const float*)d_in[15];
    const float* W_m1   = (const float*)d_in[16];
    const float* W_m2   = (const float*)d_in[17];
    const float* b_k1   = (const float*)d_in[18];
    const float* b_q1   = (const float*)d_in[19];
    const float* b_v1   = (const float*)d_in[20];
    const float* b_a1   = (const float*)d_in[21];
    const float* b_k23  = (const float*)d_in[22];
    const float* b_q23  = (const float*)d_in[23];
    const float* b_v23  = (const float*)d_in[24];
    const float* b_a23  = (const float*)d_in[25];
    const float* skip23 = (const float*)d_in[26];
    const float* b_m1   = (const float*)d_in[27];
    const float* b_m2   = (const float*)d_in[28];
    const float* p_rel1 = (const float*)d_in[29];
    const float* p_rel23= (const float*)d_in[30];

    const int N = N_NODES_C;
    const int E = in_sizes[1] / 2;
    const int F = in_sizes[0] / N;            // 512
    const long NN = (long)N * HDIM;           // 6.4M

    // workspace layout (f32 units); total == 230,898,304 B (same as round-1 need)
    float* ws   = (float*)d_ws;
    float* QKV  = ws;                          // 50000*640 = 32,000,000
    float* ACC  = QKV + (long)N * 640;         // 6,400,000
    float* NUM  = ACC + NN;                    // 6,400,000 (aliases WT)
    float* H1   = NUM + NN;                    // 6,400,000
    float* H2   = H1 + NN;                     // 6,400,000
    float* DEN  = H2 + NN;                     // 100,000
    float* S    = DEN + (long)N * 2;           // 8192
    float* GM   = S + N_GRAPHS_C * HDIM;       // 8192
    float* M1   = GM + N_GRAPHS_C * HDIM;      // 8192
    float* WT   = NUM;                         // up to 640*512, dead before NUM used
    float* B640 = NUM + 400000;                // 640, same lifetime as WT
    float* WaT  = QKV;                         // 16384, QKV dead by out-proj time
    size_t needed = (size_t)((long)N * 640 + 4 * NN + (long)N * 2 + 3L * N_GRAPHS_C * HDIM) * sizeof(float);
    if (ws_size < needed) return;

    auto mfma_gemm = [&](const float* A, int lda, const float* BTp, int ldbt,
                         const float* bias, float* Cp, int ldc, int M, int Nc, int K,
                         int epi, const float* gate, const float* xprev) {
        dim3 grid(Nc / GBN, (M + GBM - 1) / GBM);
        gemm_mfma_split<<<grid, 256, 0, stream>>>(A, lda, BTp, ldbt, bias, Cp, ldc,
                                                  M, Nc, K, epi, gate, xprev);
    };

    auto run_layer = [&](const float* hin, int Fin,
                         const float* Wk, const float* bk,
                         const float* Wq, const float* bq,
                         const float* Wv, const float* bv,
                         const float* arel, const float* mrel, const float* prel,
                         const float* Wa, const float* ba,
                         const float* gate, float* hout) {
        int tot = Fin * 640;
        build_wbigT<<<(tot + 255) / 256, 256, 0, stream>>>(Wq, bq, Wk, bk, Wv, bv,
                                                           arel, mrel, WT, B640, Fin);
        mfma_gemm(hin, Fin, WT, Fin, B640, QKV, 640, N, 640, Fin, 0, nullptr, nullptr);
        hipMemsetAsync(ACC, 0, NN * sizeof(float), stream);
        for (int r = 0; r < 2; ++r) {
            const int* srcp = (r == 0) ? e0 : e1;
            const int* dstp = srcp + E;
            hipMemsetAsync(NUM, 0, NN * sizeof(float), stream);
            hipMemsetAsync(DEN, 0, (size_t)N * 2 * sizeof(float), stream);
            int waves = E * 2;
            int blocks = (waves + 3) / 4;
            edge_attn_kernel<<<blocks, 256, 0, stream>>>(srcp, dstp, QKV,
                QKV + 128 + r * 128, QKV + 384 + r * 128, prel + r * 2, NUM, DEN, E);
            scale_acc_kernel<<<(int)((NN + 255) / 256), 256, 0, stream>>>(NUM, DEN, ACC, (int)NN);
        }
        gelu_kernel<<<(int)((NN + 255) / 256), 256, 0, stream>>>(ACC, (int)NN);
        transpose128<<<64, 256, 0, stream>>>(Wa, WaT);
        mfma_gemm(ACC, 128, WaT, 128, ba, hout, 128, N, 128, 128,
                  gate ? 2 : 1, gate, hin);
    };

    run_layer(x, F, W_k1, b_k1, W_q1, b_q1, W_v1, b_v1,
              a_rel1, m_rel1, p_rel1, W_a1, b_a1, nullptr, H1);
    run_layer(H1, HDIM, W_k23, b_k23, W_q23, b_q23, W_v23, b_v23,
              a_rel23, m_rel23, p_rel23, W_a23, b_a23, skip23, H2);
    run_layer(H2, HDIM, W_k23 + 16384, b_k23 + 128, W_q23 + 16384, b_q23 + 128,
              W_v23 + 16384, b_v23 + 128, a_rel23 + 16384, m_rel23 + 16384,
              p_rel23 + 4, W_a23 + 16384, b_a23 + 128, skip23 + 1, H1);

    hipMemsetAsync(S, 0, (size_t)N_GRAPHS_C * HDIM * sizeof(float), stream);
    dim3 pg(N_GRAPHS_C, 8);
    pool_kernel<<<pg, HDIM, 0, stream>>>(H1, batch, S, N);
    pool_finalize<<<N_GRAPHS_C, HDIM, 0, stream>>>(S, batch, GM, N);

    {
        dim3 g1(128 / BN, 1);
        gemm_bias_kernel<<<g1, 256, 0, stream>>>(GM, 128, W_m1, 128, b_m1, M1, 128,
                                                 N_GRAPHS_C, 128, 1);
        dim3 g2(256 / BN, 1);
        gemm_bias_kernel<<<g2, 256, 0, stream>>>(M1, 128, W_m2, 256, b_m2,
                                                 (float*)d_out, 256, N_GRAPHS_C, 128, 0);
    }
}

// Round 3
// 1282.426 us; speedup vs baseline: 1.4627x; 1.1976x over previous
//
#include <hip/hip_runtime.h>
#include <math.h>

#define N_NODES_C 50000
#define N_GRAPHS_C 64
#define HDIM 128

typedef short bf16x8 __attribute__((ext_vector_type(8)));
typedef short shortx4 __attribute__((ext_vector_type(4)));
typedef float floatx4 __attribute__((ext_vector_type(4)));

// split f32 -> hi (truncated bf16) + lo (bf16 of exact residual)
__device__ inline void cvt_pair(float x, short& h, short& l) {
    union { float f; unsigned u; } a; a.f = x;
    h = (short)(a.u >> 16);
    union { unsigned u; float f; } b; b.u = a.u & 0xFFFF0000u;
    union { float f; unsigned u; } c; c.f = x - b.f;   // exact residual
    l = (short)(c.u >> 16);
}

// ============ split-bf16 MFMA GEMM with register prefetch ============
#define GBM 128
#define GBN 128
#define GBK 32
#define BKP 40   // padded LDS k-stride (80 B, 16B-aligned, ~2-way banks)

__global__ __launch_bounds__(256, 2) void gemm_mfma_split(
    const float* __restrict__ A, int lda,
    const float* __restrict__ BT, int ldbt,
    const float* __restrict__ bias,
    float* __restrict__ C, int ldc,
    int M, int Ntot, int K,
    int epilogue,                        // 0 none, 1 relu, 2 gated-skip + relu
    const float* __restrict__ skipGate,
    const float* __restrict__ Xprev)
{
    __shared__ __align__(16) short AsH[GBM * BKP];
    __shared__ __align__(16) short AsL[GBM * BKP];
    __shared__ __align__(16) short BsH[GBN * BKP];
    __shared__ __align__(16) short BsL[GBN * BKP];

    const int t = threadIdx.x;
    const int lane = t & 63;
    const int wave = t >> 6;
    const int wm = wave & 1, wn = wave >> 1;
    const int quad = lane >> 4, l15 = lane & 15;
    const long row0 = (long)blockIdx.y * GBM;
    const long col0 = (long)blockIdx.x * GBN;

    const int srow = t >> 3;          // 0..31
    const int sk = (t & 7) << 2;      // 0,4,..,28

    floatx4 acc[4][4];
    #pragma unroll
    for (int i = 0; i < 4; ++i)
        #pragma unroll
        for (int j = 0; j < 4; ++j)
            acc[i][j] = (floatx4){0.f, 0.f, 0.f, 0.f};

    float4 ra[4], rb[4];
    const float4 fz = {0.f, 0.f, 0.f, 0.f};

    // prologue: load tile 0 into registers
    #pragma unroll
    for (int p = 0; p < 4; ++p) {
        int r = p * 32 + srow;
        long gr = row0 + r;
        ra[p] = (gr < M) ? *(const float4*)(A + gr * lda + sk) : fz;
        long gc = col0 + r;
        rb[p] = (gc < Ntot) ? *(const float4*)(BT + gc * ldbt + sk) : fz;
    }

    for (int k0 = 0; k0 < K; k0 += GBK) {
        // convert + store staged registers to LDS
        #pragma unroll
        for (int p = 0; p < 4; ++p) {
            int off = (p * 32 + srow) * BKP + sk;
            short h0, h1, h2, h3, l0, l1, l2, l3;
            cvt_pair(ra[p].x, h0, l0); cvt_pair(ra[p].y, h1, l1);
            cvt_pair(ra[p].z, h2, l2); cvt_pair(ra[p].w, h3, l3);
            *(shortx4*)&AsH[off] = (shortx4){h0, h1, h2, h3};
            *(shortx4*)&AsL[off] = (shortx4){l0, l1, l2, l3};
            cvt_pair(rb[p].x, h0, l0); cvt_pair(rb[p].y, h1, l1);
            cvt_pair(rb[p].z, h2, l2); cvt_pair(rb[p].w, h3, l3);
            *(shortx4*)&BsH[off] = (shortx4){h0, h1, h2, h3};
            *(shortx4*)&BsL[off] = (shortx4){l0, l1, l2, l3};
        }
        __syncthreads();

        // prefetch next tile into registers (hidden behind MFMA below)
        if (k0 + GBK < K) {
            int kn = k0 + GBK + sk;
            #pragma unroll
            for (int p = 0; p < 4; ++p) {
                int r = p * 32 + srow;
                long gr = row0 + r;
                ra[p] = (gr < M) ? *(const float4*)(A + gr * lda + kn) : fz;
                long gc = col0 + r;
                rb[p] = (gc < Ntot) ? *(const float4*)(BT + gc * ldbt + kn) : fz;
            }
        }

        bf16x8 aH[4], aL[4], bH[4], bL[4];
        #pragma unroll
        for (int i = 0; i < 4; ++i) {
            int off = (wm * 64 + i * 16 + l15) * BKP + quad * 8;
            aH[i] = *(const bf16x8*)&AsH[off];
            aL[i] = *(const bf16x8*)&AsL[off];
        }
        #pragma unroll
        for (int j = 0; j < 4; ++j) {
            int off = (wn * 64 + j * 16 + l15) * BKP + quad * 8;
            bH[j] = *(const bf16x8*)&BsH[off];
            bL[j] = *(const bf16x8*)&BsL[off];
        }
        #pragma unroll
        for (int i = 0; i < 4; ++i)
            #pragma unroll
            for (int j = 0; j < 4; ++j) {
                acc[i][j] = __builtin_amdgcn_mfma_f32_16x16x32_bf16(aH[i], bH[j], acc[i][j], 0, 0, 0);
                acc[i][j] = __builtin_amdgcn_mfma_f32_16x16x32_bf16(aH[i], bL[j], acc[i][j], 0, 0, 0);
                acc[i][j] = __builtin_amdgcn_mfma_f32_16x16x32_bf16(aL[i], bH[j], acc[i][j], 0, 0, 0);
            }
        __syncthreads();
    }

    float gate = 0.f;
    if (epilogue == 2) gate = 1.f / (1.f + expf(-skipGate[0]));

    #pragma unroll
    for (int i = 0; i < 4; ++i) {
        #pragma unroll
        for (int rr = 0; rr < 4; ++rr) {
            long grow = row0 + wm * 64 + i * 16 + quad * 4 + rr;
            if (grow >= M) continue;
            #pragma unroll
            for (int j = 0; j < 4; ++j) {
                long gcol = col0 + wn * 64 + j * 16 + l15;
                if (gcol >= Ntot) continue;
                float v = acc[i][j][rr];
                if (bias) v += bias[gcol];
                if (epilogue == 2) v = gate * v + (1.f - gate) * Xprev[grow * ldc + gcol];
                if (epilogue >= 1) v = fmaxf(v, 0.f);
                C[grow * ldc + gcol] = v;
            }
        }
    }
}

// ============ build fused transposed weight WbigT[640, F] + bias640 ============
// cols: [0,128) q | [128,384) k_r (r,h,e) | [384,640) v_r
__global__ void build_wbigT(
    const float* __restrict__ Wq, const float* __restrict__ bq,
    const float* __restrict__ Wk, const float* __restrict__ bk,
    const float* __restrict__ Wv, const float* __restrict__ bv,
    const float* __restrict__ arel, const float* __restrict__ mrel,
    float* __restrict__ WT, float* __restrict__ bias, int F)
{
    int idx = blockIdx.x * 256 + threadIdx.x;
    if (idx >= F * 640) return;
    int c = idx / F;
    int f = idx - c * F;
    float w, b = 0.f;
    if (c < 128) {
        w = Wq[(long)f * 128 + c];
        b = bq[c];
    } else {
        int cc = c - 128;
        const float* Wsrc; const float* bsrc; const float* T;
        if (cc < 256) { Wsrc = Wk; bsrc = bk; T = arel; }
        else { cc -= 256; Wsrc = Wv; bsrc = bv; T = mrel; }
        int r = cc >> 7, j = cc & 127, h = j >> 6, e = j & 63;
        const float* Trow = T + ((long)(r * 2 + h) * 4096 + e);
        const float* Wrow = Wsrc + (long)f * 128 + h * 64;
        float s = 0.f;
        for (int d = 0; d < 64; ++d) s += Wrow[d] * Trow[(long)d * 64];
        w = s;
        if (f == 0) {
            float sb = 0.f;
            const float* brow = bsrc + h * 64;
            for (int d = 0; d < 64; ++d) sb += brow[d] * Trow[(long)d * 64];
            b = sb;
        }
    }
    WT[idx] = w;
    if (f == 0) bias[c] = b;
}

__global__ void transpose128(const float* __restrict__ W, float* __restrict__ WT)
{
    int idx = blockIdx.x * 256 + threadIdx.x;   // 16384
    int c = idx >> 7, f = idx & 127;
    WT[idx] = W[f * 128 + c];
}

// ============ edge attention: one wave per (edge, head); q/kr/vr ld = 640 ============
__global__ __launch_bounds__(256) void edge_attn_kernel(
    const int* __restrict__ src, const int* __restrict__ dst,
    const float* __restrict__ q, const float* __restrict__ kr,
    const float* __restrict__ vr,
    const float* __restrict__ p_rel,
    float* __restrict__ num, float* __restrict__ den,
    int E)
{
    int wid = (int)((blockIdx.x * 256 + threadIdx.x) >> 6);
    int lane = threadIdx.x & 63;
    int e = wid >> 1;
    int h = wid & 1;
    if (e >= E) return;

    int s = src[e];
    int d = dst[e];
    long bs = (long)s * 640 + h * 64;
    long bd = (long)d * 640 + h * 64;

    float p = q[bd + lane] * kr[bs + lane];
    #pragma unroll
    for (int off = 32; off; off >>= 1) p += __shfl_xor(p, off, 64);

    float w = expf(p * p_rel[h] * 0.125f);   // 1/sqrt(64)

    atomicAdd(&num[(long)d * 128 + h * 64 + lane], w * vr[bs + lane]);
    if (lane == 0) atomicAdd(&den[d * 2 + h], w);
}

// ============ fused: out = gelu(num0/den0 + num1/den1) ============
__global__ __launch_bounds__(256) void attn_finalize_kernel(
    const float* __restrict__ num0, const float* __restrict__ den0,
    const float* __restrict__ num1, const float* __restrict__ den1,
    float* __restrict__ out, int total)
{
    int i = blockIdx.x * 256 + threadIdx.x;
    if (i >= total) return;
    int dh = i >> 6;
    float v = num0[i] / (den0[dh] + 1e-16f) + num1[i] / (den1[dh] + 1e-16f);
    out[i] = 0.5f * v * (1.f + erff(v * 0.70710678118654752f));
}

// ============ f32 vector GEMM kept for tiny MLP ============
#define BM 64
#define BN 64
#define BK 16
__global__ __launch_bounds__(256) void gemm_bias_kernel(
    const float* __restrict__ A, int lda,
    const float* __restrict__ B, int ldb,
    const float* __restrict__ bias,
    float* __restrict__ C, int ldc,
    int M, int K, int epilogue)
{
    __shared__ float As[BK][BM + 4];
    __shared__ float Bs[BK][BN + 4];
    const int t = threadIdx.x;
    const int row0 = blockIdx.y * BM;
    const int col0 = blockIdx.x * BN;
    const int tm = (t >> 4) << 2;
    const int tn = (t & 15) << 2;
    float acc[4][4] = {};
    for (int k0 = 0; k0 < K; k0 += BK) {
        #pragma unroll
        for (int i = 0; i < 4; ++i) {
            int idx = t + i * 256;
            int m = idx >> 4, kk = idx & 15;
            int gm = row0 + m;
            As[kk][m] = (gm < M) ? A[(long)gm * lda + (k0 + kk)] : 0.f;
        }
        #pragma unroll
        for (int i = 0; i < 4; ++i) {
            int idx = t + i * 256;
            int kk = idx >> 6, n = idx & 63;
            Bs[kk][n] = B[(long)(k0 + kk) * ldb + (col0 + n)];
        }
        __syncthreads();
        #pragma unroll
        for (int kk = 0; kk < BK; ++kk) {
            float a[4], b[4];
            #pragma unroll
            for (int i = 0; i < 4; ++i) a[i] = As[kk][tm + i];
            #pragma unroll
            for (int j = 0; j < 4; ++j) b[j] = Bs[kk][tn + j];
            #pragma unroll
            for (int i = 0; i < 4; ++i)
                #pragma unroll
                for (int j = 0; j < 4; ++j)
                    acc[i][j] = fmaf(a[i], b[j], acc[i][j]);
        }
        __syncthreads();
    }
    #pragma unroll
    for (int i = 0; i < 4; ++i) {
        int gm = row0 + tm + i;
        if (gm >= M) continue;
        #pragma unroll
        for (int j = 0; j < 4; ++j) {
            int gn = col0 + tn + j;
            float v = acc[i][j];
            if (bias) v += bias[gn];
            if (epilogue >= 1) v = fmaxf(v, 0.f);
            C[(long)gm * ldc + gn] = v;
        }
    }
}

// ============ pooling ============
__device__ inline int lower_bound_i(const int* __restrict__ a, int n, int v)
{
    int lo = 0, hi = n;
    while (lo < hi) { int mid = (lo + hi) >> 1; if (a[mid] < v) lo = mid + 1; else hi = mid; }
    return lo;
}

__global__ void pool_kernel(const float* __restrict__ h, const int* __restrict__ batch,
                            float* __restrict__ s, int N)
{
    int g = blockIdx.x, part = blockIdx.y, c = threadIdx.x;
    int start = lower_bound_i(batch, N, g);
    int end = lower_bound_i(batch, N, g + 1);
    int cnt = end - start, parts = gridDim.y;
    int chunk = (cnt + parts - 1) / parts;
    int a = start + part * chunk;
    int b = a + chunk; if (b > end) b = end;
    if (a >= b) return;
    float sum = 0.f;
    for (int n = a; n < b; ++n) sum += h[(long)n * HDIM + c];
    atomicAdd(&s[g * HDIM + c], sum);
}

__global__ void pool_finalize(const float* __restrict__ s, const int* __restrict__ batch,
                              float* __restrict__ g_out, int N)
{
    int g = blockIdx.x, c = threadIdx.x;
    int start = lower_bound_i(batch, N, g);
    int end = lower_bound_i(batch, N, g + 1);
    float cnt = (float)((end - start) > 1 ? (end - start) : 1);
    g_out[g * HDIM + c] = s[g * HDIM + c] / cnt;
}

// ============ host ============
extern "C" void kernel_launch(void* const* d_in, const int* in_sizes, int n_in,
                              void* d_out, int out_size, void* d_ws, size_t ws_size,
                              hipStream_t stream)
{
    const float* x      = (const float*)d_in[0];
    const int*   e0     = (const int*)d_in[1];
    const int*   e1     = (const int*)d_in[2];
    const int*   batch  = (const int*)d_in[3];
    const float* W_k1   = (const float*)d_in[4];
    const float* W_q1   = (const float*)d_in[5];
    const float* W_v1   = (const float*)d_in[6];
    const float* a_rel1 = (const float*)d_in[7];
    const float* m_rel1 = (const float*)d_in[8];
    const float* W_a1   = (const float*)d_in[9];
    const float* W_k23  = (const float*)d_in[10];
    const float* W_q23  = (const float*)d_in[11];
    const float* W_v23  = (const float*)d_in[12];
    const float* a_rel23= (const float*)d_in[13];
    const float* m_rel23= (const float*)d_in[14];
    const float* W_a23  = (const float*)d_in[15];
    const float* W_m1   = (const float*)d_in[16];
    const float* W_m2   = (const float*)d_in[17];
    const float* b_k1   = (const float*)d_in[18];
    const float* b_q1   = (const float*)d_in[19];
    const float* b_v1   = (const float*)d_in[20];
    const float* b_a1   = (const float*)d_in[21];
    const float* b_k23  = (const float*)d_in[22];
    const float* b_q23  = (const float*)d_in[23];
    const float* b_v23  = (const float*)d_in[24];
    const float* b_a23  = (const float*)d_in[25];
    const float* skip23 = (const float*)d_in[26];
    const float* b_m1   = (const float*)d_in[27];
    const float* b_m2   = (const float*)d_in[28];
    const float* p_rel1 = (const float*)d_in[29];
    const float* p_rel23= (const float*)d_in[30];

    const int N = N_NODES_C;
    const int E = in_sizes[1] / 2;
    const int F = in_sizes[0] / N;            // 512
    const long NN = (long)N * HDIM;           // 6.4M

    float* ws   = (float*)d_ws;
    float* QKV  = ws;                          // 50000*640
    float* ACC  = QKV + (long)N * 640;         // NN  (doubles as NUM1)
    float* NUM  = ACC + NN;                    // NN  (NUM0; start aliases WT)
    float* H1   = NUM + NN;                    // NN
    float* H2   = H1 + NN;                     // NN
    float* DEN  = H2 + NN;                     // N*2 (DEN0)
    float* S    = DEN + (long)N * 2;
    float* GM   = S + N_GRAPHS_C * HDIM;
    float* M1   = GM + N_GRAPHS_C * HDIM;
    float* WT   = NUM;                         // 640*F, dead before NUM0 used
    float* B640 = NUM + 400000;                // 640, same lifetime as WT
    float* WaT  = QKV;                         // 16384, QKV dead by out-proj time
    size_t needed = (size_t)((long)N * 640 + 4 * NN + (long)N * 2 + 3L * N_GRAPHS_C * HDIM) * sizeof(float);
    if (ws_size < needed) return;

    auto mfma_gemm = [&](const float* A, int lda, const float* BTp, int ldbt,
                         const float* bias, float* Cp, int ldc, int M, int Nc, int K,
                         int epi, const float* gate, const float* xprev) {
        dim3 grid(Nc / GBN, (M + GBM - 1) / GBM);
        gemm_mfma_split<<<grid, 256, 0, stream>>>(A, lda, BTp, ldbt, bias, Cp, ldc,
                                                  M, Nc, K, epi, gate, xprev);
    };

    auto run_layer = [&](const float* hin, int Fin,
                         const float* Wk, const float* bk,
                         const float* Wq, const float* bq,
                         const float* Wv, const float* bv,
                         const float* arel, const float* mrel, const float* prel,
                         const float* Wa, const float* ba,
                         const float* gate, float* hout) {
        int tot = Fin * 640;
        build_wbigT<<<(tot + 255) / 256, 256, 0, stream>>>(Wq, bq, Wk, bk, Wv, bv,
                                                           arel, mrel, WT, B640, Fin);
        mfma_gemm(hin, Fin, WT, Fin, B640, QKV, 640, N, 640, Fin, 0, nullptr, nullptr);

        float* NUM0 = NUM;  float* DEN0 = DEN;
        float* NUM1 = ACC;  float* DEN1 = hout;   // hout written only at out-proj (after finalize)
        hipMemsetAsync(NUM0, 0, NN * sizeof(float), stream);
        hipMemsetAsync(NUM1, 0, NN * sizeof(float), stream);
        hipMemsetAsync(DEN0, 0, (size_t)N * 2 * sizeof(float), stream);
        hipMemsetAsync(DEN1, 0, (size_t)N * 2 * sizeof(float), stream);

        int waves = E * 2;
        int blocks = (waves + 3) / 4;
        edge_attn_kernel<<<blocks, 256, 0, stream>>>(e0 == nullptr ? e0 : e0, e0 + E, QKV,
            QKV + 128, QKV + 384, prel, NUM0, DEN0, E);
        edge_attn_kernel<<<blocks, 256, 0, stream>>>(e1, e1 + E, QKV,
            QKV + 128 + 128, QKV + 384 + 128, prel + 2, NUM1, DEN1, E);

        // ACC = gelu(num0/den0 + num1/den1); out aliases NUM1 elementwise (safe)
        attn_finalize_kernel<<<(int)((NN + 255) / 256), 256, 0, stream>>>(
            NUM0, DEN0, NUM1, DEN1, ACC, (int)NN);

        transpose128<<<64, 256, 0, stream>>>(Wa, WaT);
        mfma_gemm(ACC, 128, WaT, 128, ba, hout, 128, N, 128, 128,
                  gate ? 2 : 1, gate, hin);
    };

    run_layer(x, F, W_k1, b_k1, W_q1, b_q1, W_v1, b_v1,
              a_rel1, m_rel1, p_rel1, W_a1, b_a1, nullptr, H1);
    run_layer(H1, HDIM, W_k23, b_k23, W_q23, b_q23, W_v23, b_v23,
              a_rel23, m_rel23, p_rel23, W_a23, b_a23, skip23, H2);
    run_layer(H2, HDIM, W_k23 + 16384, b_k23 + 128, W_q23 + 16384, b_q23 + 128,
              W_v23 + 16384, b_v23 + 128, a_rel23 + 16384, m_rel23 + 16384,
              p_rel23 + 4, W_a23 + 16384, b_a23 + 128, skip23 + 1, H1);

    hipMemsetAsync(S, 0, (size_t)N_GRAPHS_C * HDIM * sizeof(float), stream);
    dim3 pg(N_GRAPHS_C, 8);
    pool_kernel<<<pg, HDIM, 0, stream>>>(H1, batch, S, N);
    pool_finalize<<<N_GRAPHS_C, HDIM, 0, stream>>>(S, batch, GM, N);

    {
        dim3 g1(128 / BN, 1);
        gemm_bias_kernel<<<g1, 256, 0, stream>>>(GM, 128, W_m1, 128, b_m1, M1, 128,
                                                 N_GRAPHS_C, 128, 1);
        dim3 g2(256 / BN, 1);
        gemm_bias_kernel<<<g2, 256, 0, stream>>>(M1, 128, W_m2, 256, b_m2,
                                                 (float*)d_out, 256, N_GRAPHS_C, 128, 0);
    }
}